// Round 3
// baseline (10.153 us; speedup 1.0000x reference)
//
#include <hip/hip_runtime.h>

// out[b, q] = prod_{i=0}^{N-1-q} cos(x[b, i])
//
// Closed form of the circuit: RX gives independent bits with
// E[(-1)^{b_i}] = cos(x_i); CNOT ladder makes bit j the prefix XOR; label
// reversal maps column q to qubit n-1-q. So out is a reversed cosine
// prefix product per row.
//
// R2: __cosf swap gained 1.68us (11.44 -> 9.77). Remaining tail: 28 scalar
// dword memory ops/thread. Rows are 56B = 8B-aligned -> float2 vectorize
// (7 loads + 7 stores), all outputs computed to regs before storing.

#define NQ 14
#define BATCH 2048

__global__ void QGate_65481071401635_kernel(const float* __restrict__ x,
                                            float* __restrict__ out) {
    int b = blockIdx.x * blockDim.x + threadIdx.x;
    if (b >= BATCH) return;
    const float2* xr = reinterpret_cast<const float2*>(x + b * NQ);
    float2* orow = reinterpret_cast<float2*>(out + b * NQ);

    // 7 x 8B loads (independent, pipelined)
    float2 v[NQ / 2];
#pragma unroll
    for (int i = 0; i < NQ / 2; ++i) v[i] = xr[i];

    // prefix product of cosines
    float pr[NQ];
    float p = 1.0f;
#pragma unroll
    for (int i = 0; i < NQ / 2; ++i) {
        p *= __cosf(v[i].x);
        pr[2 * i] = p;
        p *= __cosf(v[i].y);
        pr[2 * i + 1] = p;
    }

    // out[q] = prefix through (NQ-1-q); 7 x 8B stores
#pragma unroll
    for (int i = 0; i < NQ / 2; ++i) {
        float2 w;
        w.x = pr[NQ - 1 - 2 * i];
        w.y = pr[NQ - 2 - 2 * i];
        orow[i] = w;
    }
}

extern "C" void kernel_launch(void* const* d_in, const int* in_sizes, int n_in,
                              void* d_out, int out_size, void* d_ws, size_t ws_size,
                              hipStream_t stream) {
    const float* x = (const float*)d_in[0];
    float* out = (float*)d_out;
    const int block = 64;
    const int grid = (BATCH + block - 1) / block;  // 32 blocks
    QGate_65481071401635_kernel<<<grid, block, 0, stream>>>(x, out);
}

// Round 4
// 9.769 us; speedup vs baseline: 1.0394x; 1.0394x over previous
//
#include <hip/hip_runtime.h>

// out[b, q] = prod_{i=0}^{N-1-q} cos(x[b, i])
//
// Closed form of the circuit: RX gives independent bits with
// E[(-1)^{b_i}] = cos(x_i); the CNOT ladder makes measured bit j the prefix
// XOR b_0^...^b_j; the little-endian label reversal maps output column q to
// qubit n-1-q. So out is a reversed cosine prefix-product per row.
//
// R3 post-mortem: float2 vectorization neutral (noise). Kernel exec is
// sub-us; dur_us ~10us is the graph-replay overhead floor (kernel never
// appears in rocprof top-5). Reverting to the best/simplest R2 form.

#define NQ 14
#define BATCH 2048

__global__ void QGate_65481071401635_kernel(const float* __restrict__ x,
                                            float* __restrict__ out) {
    int b = blockIdx.x * blockDim.x + threadIdx.x;
    if (b >= BATCH) return;
    const float* xr = x + b * NQ;
    float* orow = out + b * NQ;

    float c[NQ];
#pragma unroll
    for (int i = 0; i < NQ; ++i) {
        c[i] = __cosf(xr[i]);  // v_cos_f32, independent -> pipelined
    }
    float p = 1.0f;
#pragma unroll
    for (int i = 0; i < NQ; ++i) {
        p *= c[i];
        orow[NQ - 1 - i] = p;  // out[b, n-1-i] = prefix product through i
    }
}

extern "C" void kernel_launch(void* const* d_in, const int* in_sizes, int n_in,
                              void* d_out, int out_size, void* d_ws, size_t ws_size,
                              hipStream_t stream) {
    const float* x = (const float*)d_in[0];
    float* out = (float*)d_out;
    const int block = 64;
    const int grid = (BATCH + block - 1) / block;  // 32 blocks
    QGate_65481071401635_kernel<<<grid, block, 0, stream>>>(x, out);
}